// Round 11
// baseline (263.573 us; speedup 1.0000x reference)
//
#include <hip/hip_runtime.h>

// B=4, S=2048, D=768, H=12, HD=64. I/O f32; internal bf16 MFMA.
// ws: wqkv_t [2304][768] | wout_t [768][768] | q_ws, k_ws [B,H,S,64] (bf16)
// d_out scratch: lower half Vt (bf16 [B,H,HD,S], TRUE s order), upper half x_bf16.
// attn output overwrites q_ws rows in place (block-local; race-free).
// Q is pre-scaled by SCALE*log2(e) at the QKV epilogue (softmax uses raw exp2).
#define BB 4
#define SS 2048
#define DD 768
#define HH 12
#define HDIM 64

using bf16_t = __bf16;
typedef __bf16 bf16x8 __attribute__((ext_vector_type(8)));
typedef __bf16 bf16x4 __attribute__((ext_vector_type(4)));
typedef __bf16 bf16x2 __attribute__((ext_vector_type(2)));
typedef float f32x4 __attribute__((ext_vector_type(4)));
typedef float f32x16 __attribute__((ext_vector_type(16)));
typedef unsigned int u32;
typedef unsigned int u32x4 __attribute__((ext_vector_type(4)));

// async global->LDS 16B per lane; LDS dst is wave-uniform base + lane*16
static __device__ __forceinline__ void cp16(void* lds, const void* g) {
  __builtin_amdgcn_global_load_lds(
      (const __attribute__((address_space(1))) u32*)g,
      (__attribute__((address_space(3))) u32*)lds, 16, 0, 0);
}

// ---------------------------------------------------------------------------
// x f32 [M,K] -> bf16 (contiguous copy+convert)
// ---------------------------------------------------------------------------
__global__ void cvt_x(const float* __restrict__ in, bf16_t* __restrict__ out) {
  const size_t i = ((size_t)blockIdx.x * 256 + threadIdx.x) * 8;
  f32x4 f0 = *(const f32x4*)(in + i);
  f32x4 f1 = *(const f32x4*)(in + i + 4);
  bf16x8 v;
#pragma unroll
  for (int j = 0; j < 4; j++) { v[j] = (bf16_t)f0[j]; v[4 + j] = (bf16_t)f1[j]; }
  *(bf16x8*)(out + i) = v;
}

// ---------------------------------------------------------------------------
// Weight transpose + f32->bf16: in [K][N] f32 -> out [N][K] bf16
// ---------------------------------------------------------------------------
__global__ void wt_transpose(const float* __restrict__ in, bf16_t* __restrict__ out,
                             int K, int N) {
  __shared__ bf16_t tile[64][65];
  const int n0 = blockIdx.x * 64, k0 = blockIdx.y * 64;
  const int t = threadIdx.x;       // 256 threads
  const int r = t >> 2;            // 0..63
  const int c0 = (t & 3) * 16;     // 0,16,32,48
  const float* src = in + (size_t)(k0 + r) * N + n0 + c0;
#pragma unroll
  for (int q = 0; q < 4; q++) {
    f32x4 f = *(const f32x4*)(src + q * 4);
#pragma unroll
    for (int j = 0; j < 4; j++) tile[r][c0 + q * 4 + j] = (bf16_t)f[j];
  }
  __syncthreads();
  bf16x8 o0, o1;
#pragma unroll
  for (int j = 0; j < 8; j++) { o0[j] = tile[c0 + j][r]; o1[j] = tile[c0 + 8 + j][r]; }
  *(bf16x8*)(out + (size_t)(n0 + r) * K + k0 + c0) = o0;
  *(bf16x8*)(out + (size_t)(n0 + r) * K + k0 + c0 + 8) = o1;
}

// ---------------------------------------------------------------------------
// QKV GEMM: C[8192,2304] = x_bf16[8192,768] @ wqkv_t[2304,768]^T.
// 256x256 tile, BK=64, 512 threads = 8 waves (2M x 4N), dbuf LDS 128 KB,
// PHASE-INTERLEAVED COUNTED-VMCNT schedule (T3+T4; m201/m218 mechanism —
// r10 showed naive 2-barrier 256^2 collapses at 1 block/CU, while m201's
// 8-phase 256^2 hits 1563 TF at the same ~1 block/CU on this chip).
//
// Per K-tile t: 4 phases = 4 C-quadrants. Quadrant q reads A rows
// [32q,32q+32) of each 128-row half + ALL of B. Tile t+1 is staged in
// death-order during tile t (per wave, 2 cp16/phase, 8/tile):
//   phase0: B loads #0,#1   phase1: B #2,#3
//   phase2: A #0,#2 (quads 0,1 rows)   phase3: A #1,#3 (quads 2,3 rows)
// (A load c covers rows [c*64 .. c*64+63] via row = (c*8+wave)*8+srow.)
// Gates (per-wave vmcnt ledger, audited t=0 / steady / t=NT-1):
//   boundary: vmcnt(2) -> B(t)+A02(t) landed, A13(t) still in flight
//   mid-tile: vmcnt(4) -> A13(t) landed, B(t+1) still in flight
// Never drains to 0 until the last tile. WAR: every stage target's last
// reader finished >=1 barrier earlier (B: prev tile, all phases before
// boundary barrier; A02: prev tile phases 0,1, two barriers back; A13:
// prev tile phase 3, one barrier back). sched_barrier(0) after each raw
// s_barrier pins each phase's ds_reads/MFMAs inside the phase (rule #18).
// Swizzle: r6's measured-zero-conflict 64-wide pair (stage ((lane&7)^srow),
// read (kk*4+quad)^(l15&7)). Epilogue: r10's verified-correct scatter.
// ---------------------------------------------------------------------------
__global__ __launch_bounds__(512, 2)
void gemm_qkv(const bf16_t* __restrict__ A, const bf16_t* __restrict__ Bt,
              bf16_t* __restrict__ q_out, bf16_t* __restrict__ k_out,
              bf16_t* __restrict__ vt_out) {
  __shared__ bf16_t As[2][256][64];
  __shared__ bf16_t Bs[2][256][64];
  const int t = threadIdx.x;
  const int lane = t & 63, wave = t >> 6;          // 8 waves
  const int l15 = lane & 15, quad = lane >> 4;
  const int wm = (wave >> 2) * 128, wn = (wave & 3) * 64;
  const int K = DD;                                 // 768

  // bijective XCD-chunked remap: 288 blocks, 36/XCD, m-major decode
  const int L = blockIdx.y * 9 + blockIdx.x;
  const int v = (L & 7) * 36 + (L >> 3);
  const int m0 = (v / 9) * 256, n0 = (v % 9) * 256;

  const int srow = lane >> 3;                   // 0..7
  const int schunk = ((lane & 7) ^ srow) * 8;   // pre-swizzled source col
  const int rsw = l15 & 7;                      // read-side swizzle key

  f32x4 acc[8][4];
#pragma unroll
  for (int i = 0; i < 8; i++)
#pragma unroll
    for (int j = 0; j < 4; j++) acc[i][j] = (f32x4){0.f, 0.f, 0.f, 0.f};

  // stage load c (c in 0..3) of A or B for K-tile kt: rows (c*8+wave)*8+srow
  auto stageA = [&](int kt, int ca, int cb) {
    const int buf = kt & 1, k0 = kt * 64;
#pragma unroll
    for (int cc = 0; cc < 2; cc++) {
      const int c = cc ? cb : ca;
      cp16(&As[buf][(c * 8 + wave) * 8][0],
           A + (size_t)(m0 + (c * 8 + wave) * 8 + srow) * K + k0 + schunk);
    }
  };
  auto stageB = [&](int kt, int ca, int cb) {
    const int buf = kt & 1, k0 = kt * 64;
#pragma unroll
    for (int cc = 0; cc < 2; cc++) {
      const int c = cc ? cb : ca;
      cp16(&Bs[buf][(c * 8 + wave) * 8][0],
           Bt + (size_t)(n0 + (c * 8 + wave) * 8 + srow) * K + k0 + schunk);
    }
  };

  // one phase: compute C-quadrant q (i = 2q, 2q+1) over full K=64 of buf
  auto phase = [&](int buf, int q) {
    bf16x8 af[2][2], bfr[4][2];
#pragma unroll
    for (int il = 0; il < 2; il++)
#pragma unroll
      for (int kk = 0; kk < 2; kk++)
        af[il][kk] = *(const bf16x8*)&As[buf][wm + (q * 2 + il) * 16 + l15]
                                            [((kk * 4 + quad) ^ rsw) * 8];
#pragma unroll
    for (int j = 0; j < 4; j++)
#pragma unroll
      for (int kk = 0; kk < 2; kk++)
        bfr[j][kk] = *(const bf16x8*)&Bs[buf][wn + j * 16 + l15]
                                            [((kk * 4 + quad) ^ rsw) * 8];
    __builtin_amdgcn_s_setprio(1);
#pragma unroll
    for (int il = 0; il < 2; il++)
#pragma unroll
      for (int j = 0; j < 4; j++)
#pragma unroll
        for (int kk = 0; kk < 2; kk++)
          acc[q * 2 + il][j] = __builtin_amdgcn_mfma_f32_16x16x32_bf16(
              af[il][kk], bfr[j][kk], acc[q * 2 + il][j], 0, 0, 0);
    __builtin_amdgcn_s_setprio(0);
  };

  const int NT = K / 64;   // 12
  // prologue: stage tile 0 in death-order (same stream shape as steady state)
  stageB(0, 0, 1); stageB(0, 2, 3); stageA(0, 0, 2); stageA(0, 1, 3);

  for (int kt = 0; kt < NT; kt++) {
    const int buf = kt & 1;
    // boundary gate: oldest 6 (B(kt) + A02(kt)) landed; A13(kt) in flight
    asm volatile("s_waitcnt vmcnt(2)" ::: "memory");
    __builtin_amdgcn_s_barrier();
    __builtin_amdgcn_sched_barrier(0);
    if (kt + 1 < NT) stageB(kt + 1, 0, 1);
    phase(buf, 0);
    if (kt + 1 < NT) stageB(kt + 1, 2, 3);
    phase(buf, 1);
    // mid gate: A13(kt) landed; B(kt+1) stays in flight
    if (kt + 1 < NT) { asm volatile("s_waitcnt vmcnt(4)" ::: "memory"); }
    else             { asm volatile("s_waitcnt vmcnt(0)" ::: "memory"); }
    __builtin_amdgcn_s_barrier();
    __builtin_amdgcn_sched_barrier(0);
    if (kt + 1 < NT) stageA(kt + 1, 0, 2);
    phase(buf, 2);
    if (kt + 1 < NT) stageA(kt + 1, 1, 3);
    phase(buf, 3);
  }

  // Epilogue (r10-verified). C/D layout: row = quad*4 + reg, col = l15.
  const float QSCALE = 0.125f * 1.44269504088896340736f;  // SCALE * log2(e)
#pragma unroll
  for (int i = 0; i < 8; i++) {
    const int mbase = m0 + wm + i * 16 + quad * 4;
#pragma unroll
    for (int j = 0; j < 4; j++) {
      const int n = n0 + wn + j * 16 + l15;
#pragma unroll
      for (int r = 0; r < 4; r++) {
        const float vv = acc[i][j][r];
        const int mm = mbase + r;
        const int sel = n / DD;          // 0:Q 1:K 2:V
        const int rem = n - sel * DD;
        const int h = rem >> 6, d = rem & 63;
        const int b = mm >> 11, s = mm & 2047;
        if (sel == 2) {
          vt_out[((size_t)(b * HH + h) * HDIM + d) * SS + s] = (bf16_t)vv;
        } else {
          const size_t idx = (((size_t)(b * HH + h)) * SS + s) * HDIM + d;
          if (sel == 0) q_out[idx] = (bf16_t)(vv * QSCALE);
          else k_out[idx] = (bf16_t)vv;
        }
      }
    }
  }
}

// ---------------------------------------------------------------------------
// Output projection GEMM (r6-exact config — best measured): C = attnout @
// wout_t^T + bias. 128x128 tile, BK=64, 4 waves, dbuf LDS (64 KB), one
// barrier per K-step, prefetch issued right after it. A is bf16
// head-interleaved [B,H,S,HD] (h = k0>>6). XCD-chunked bijective swizzle.
// ---------------------------------------------------------------------------
__global__ __launch_bounds__(256, 2)
void gemm_proj(const bf16_t* __restrict__ A, const bf16_t* __restrict__ Bt,
               float* __restrict__ Cout, const float* __restrict__ bias) {
  __shared__ bf16_t As[2][128][64];
  __shared__ bf16_t Bs[2][128][64];
  const int t = threadIdx.x;
  const int lane = t & 63, wave = t >> 6;
  const int l15 = lane & 15, quad = lane >> 4;
  const int wm = (wave >> 1) * 64, wn = (wave & 1) * 64;
  const int K = DD, N = DD;

  const int nx = gridDim.x;                 // 6
  const int L = blockIdx.y * nx + blockIdx.x;
  const int chunk = (nx * gridDim.y) >> 3;  // 48
  const int v = (L & 7) * chunk + (L >> 3);
  const int m0 = (v / nx) * 128, n0 = (v % nx) * 128;

  const int srow = lane >> 3;
  const int schunk = ((lane & 7) ^ srow) * 8;
  const int rsw = l15 & 7;

  f32x4 acc[4][4];
#pragma unroll
  for (int i = 0; i < 4; i++)
#pragma unroll
    for (int j = 0; j < 4; j++) acc[i][j] = (f32x4){0.f, 0.f, 0.f, 0.f};

  auto stage = [&](int k0, int buf) {
#pragma unroll
    for (int p = 0; p < 4; p++) {
      const int row = wave * 32 + p * 8 + srow;
      const int mm = m0 + row, b = mm >> 11, s = mm & 2047, h = k0 >> 6;
      cp16(&As[buf][wave * 32 + p * 8][0],
           A + (((size_t)(b * HH + h)) * SS + s) * HDIM + schunk);
      cp16(&Bs[buf][wave * 32 + p * 8][0],
           Bt + (size_t)(n0 + row) * K + k0 + schunk);
    }
  };

  const int NT = K / 64;   // 12
  stage(0, 0);

  for (int kt = 0; kt < NT; kt++) {
    const int buf = kt & 1;
    __syncthreads();
    if (kt + 1 < NT) stage((kt + 1) * 64, buf ^ 1);
#pragma unroll
    for (int kk = 0; kk < 2; kk++) {
      bf16x8 af[4], bfr[4];
#pragma unroll
      for (int i = 0; i < 4; i++)
        af[i] = *(const bf16x8*)&As[buf][wm + i * 16 + l15][((kk * 4 + quad) ^ rsw) * 8];
#pragma unroll
      for (int j = 0; j < 4; j++)
        bfr[j] = *(const bf16x8*)&Bs[buf][wn + j * 16 + l15][((kk * 4 + quad) ^ rsw) * 8];
#pragma unroll
      for (int i = 0; i < 4; i++)
#pragma unroll
        for (int j = 0; j < 4; j++)
          acc[i][j] = __builtin_amdgcn_mfma_f32_16x16x32_bf16(af[i], bfr[j], acc[i][j], 0, 0, 0);
    }
  }

  // Epilogue: f32 + bias, coalesced rows.
#pragma unroll
  for (int i = 0; i < 4; i++) {
    const int mbase = m0 + wm + i * 16 + quad * 4;
#pragma unroll
    for (int j = 0; j < 4; j++) {
      const int n = n0 + wn + j * 16 + l15;
#pragma unroll
      for (int r = 0; r < 4; r++)
        Cout[(size_t)(mbase + r) * N + n] = acc[i][j][r] + bias[n];
    }
  }
}

// ---------------------------------------------------------------------------
// Flash attention, streaming softmax, 32x32 MFMA, in-register P (T12),
// two-state pipeline (QK(cur+1) issued before softmax(cur) so SM VALU
// overlaps QK matrix time). Unchanged from rounds 7-10 (best measured:
// 67.4 us; conflicts fixed by the strided-phase swizzle).
// ---------------------------------------------------------------------------
__global__ __launch_bounds__(256, 3)
void attn_kernel(bf16_t* __restrict__ Qio, const bf16_t* __restrict__ Kg,
                 const bf16_t* __restrict__ Vt) {
  __shared__ bf16_t Ks[2][64][64];   // [buf][s_k][d]
  __shared__ bf16_t Vts[2][64][64];  // [buf][d][s]  (true s order)
  __shared__ float lsum[128];
  const int t = threadIdx.x;
  const int lane = t & 63, wave = t >> 6;
  const int l31 = lane & 31, hi = lane >> 5;

  // bijective XCD-aware remap: linear id -> contiguous chunk per XCD
  const int L = blockIdx.y * gridDim.x + blockIdx.x;        // 0..767
  const int v = (L & 7) * ((16 * BB * HH) / 8) + (L >> 3);  // 96 blocks/XCD
  const int bh = v >> 4;
  const int q0 = (v & 15) * 128;

  const size_t base = (size_t)bh * SS * HDIM;   // Q,K: [bh][s][d]
  const size_t baset = (size_t)bh * HDIM * SS;  // Vt:  [bh][d][s]
  const int wq = wave * 32;
  const int srow = lane >> 3;                   // 0..7
  const int rsw = (l31 & 7) ^ (l31 >> 3);       // read-side swizzle key

  // Q fragments (one-time, B-operand): qf[kd] = Q[q0+wq+l31][kd*16+hi*8 ..+7]
  bf16x8 qf[4];
#pragma unroll
  for (int kd = 0; kd < 4; kd++)
    qf[kd] = *(const bf16x8*)(Qio + base + (size_t)(q0 + wq + l31) * HDIM +
                              kd * 16 + hi * 8);

  float l_lane = 0.f;
  f32x16 o_acc[2];
#pragma unroll
  for (int dt = 0; dt < 2; dt++)
#pragma unroll
    for (int r = 0; r < 16; r++) o_acc[dt][r] = 0.f;

  f32x16 sA[2], sB[2];

  auto stageK = [&](int k0, int buf) {
#pragma unroll
    for (int p = 0; p < 2; p++) {
      const int sc = ((lane & 7) ^ srow ^ ((wave * 2 + p) & 3)) * 8;
      cp16(&Ks[buf][wave * 16 + p * 8][0],
           Kg + base + (size_t)(k0 + wave * 16 + p * 8 + srow) * HDIM + sc);
    }
  };
  auto stageV = [&](int k0, int buf) {
#pragma unroll
    for (int p = 0; p < 2; p++) {
      const int sc = ((lane & 7) ^ srow ^ ((wave * 2 + p) & 3)) * 8;
      cp16(&Vts[buf][wave * 16 + p * 8][0],
           Vt + baset + (size_t)(wave * 16 + p * 8 + srow) * SS + k0 + sc);
    }
  };

  // S^T = K @ Q^T for one 64-k tile into s[2] (swapped operands)
  auto qk = [&](int buf, f32x16 (&s)[2]) {
    __builtin_amdgcn_s_setprio(1);
#pragma unroll
    for (int ct = 0; ct < 2; ct++) {
#pragma unroll
      for (int r = 0; r < 16; r++) s[ct][r] = 0.f;
#pragma unroll
      for (int kd = 0; kd < 4; kd++) {
        bf16x8 kf = *(const bf16x8*)&Ks[buf][ct * 32 + l31][((2 * kd + hi) ^ rsw) * 8];
        s[ct] = __builtin_amdgcn_mfma_f32_32x32x16_bf16(kf, qf[kd], s[ct], 0, 0, 0);
      }
    }
    __builtin_amdgcn_s_setprio(0);
  };

  // softmax(s) in-register -> pa frags; O += P @ V[buf]
  auto smpv = [&](int buf, const f32x16 (&sT)[2]) {
    bf16x8 pa[4];
#pragma unroll
    for (int ct = 0; ct < 2; ct++) {
      float p[16];
#pragma unroll
      for (int r = 0; r < 16; r++) p[r] = __builtin_amdgcn_exp2f(sT[ct][r]);
#pragma unroll
      for (int r = 0; r < 16; r += 4)
        l_lane += (p[r] + p[r + 1]) + (p[r + 2] + p[r + 3]);
      u32 w[4][2];
#pragma unroll
      for (int g = 0; g < 4; g++)
#pragma unroll
        for (int i = 0; i < 2; i++) {
          bf16x2 pk = {(bf16_t)p[4 * g + 2 * i], (bf16_t)p[4 * g + 2 * i + 1]};
          w[g][i] = *(u32*)&pk;
        }
#pragma unroll
      for (int sub = 0; sub < 2; sub++) {
        u32 a0 = w[2 * sub][0], b0 = w[2 * sub + 1][0];
        u32 a1 = w[2 * sub][1], b1 = w[2 * sub + 1][1];
        asm volatile("v_permlane32_swap_b32 %0, %1" : "+v"(a0), "+v"(b0));
        asm volatile("v_permlane32_swap_b32 %0, %1" : "+v"(a1), "+v"(b1));
        u32x4 fr = {a0, a1, b0, b1};
        pa[ct * 2 + sub] = *(bf16x8*)&fr;
      }
    }
    __builtin_amdgcn_s_setprio(1);
#pragma unroll
    for (int kk = 0; kk < 4; kk++)
#pragma unroll
      for (int dt = 0; dt < 2; dt++) {
        bf16x8 vf = *(const bf16x8*)&Vts[buf][dt * 32 + l31][((2 * kk + hi) ^ rsw) * 8];
        o_acc[dt] = __builtin_amdgcn_mfma_f32_32x32x16_bf16(pa[kk], vf, o_acc[dt], 0, 0, 0);
      }
    __builtin_amdgcn_s_setprio(0);
  };

  // Prologue: K[0],K[1],V[0] staged; QK(0)->sA; extra barrier so the loop's
  // first stageK(2)->Ks[0] can't race another wave still reading Ks[0].
  stageK(0, 0); stageK(64, 1); stageV(0, 0);
  __syncthreads();
  qk(0, sA);
  __syncthreads();

#pragma unroll 1
  for (int it = 0; it < 30; it += 2) {
    // even: cur=it (sA), next=it+1 (sB)
    stageK((it + 2) * 64, 0);
    stageV((it + 1) * 64, 1);
    qk(1, sB);        // QK(it+1) issued EARLY; SM(it) VALU overlaps it
    smpv(0, sA);      // softmax+PV for cur=it, V in Vts[0]
    __syncthreads();
    // odd: cur=it+1 (sB), next=it+2 (sA)
    stageK((it + 3) * 64, 1);
    stageV((it + 2) * 64, 0);
    qk(0, sA);        // QK(it+2)
    smpv(1, sB);      // PV(it+1), V in Vts[1]
    __syncthreads();
  }
  // tail pair it=30,31: no more K to stage; V[31] into Vts[1]
  stageV(31 * 64, 1);
  qk(1, sB);          // QK(31)
  smpv(0, sA);        // PV(30)
  __syncthreads();
  smpv(1, sB);        // PV(31)

  // l: lane-local sum covers k-parity == hi; partner (^32) has the rest.
  const float lf = l_lane + __shfl_xor(l_lane, 32);
  lsum[wq + l31] = lf;  // both halves write the same value; own-wave region
  // O write: col = d = dt*32+l31, row = q = (r&3)+8*(r>>2)+4*hi (+wq).
#pragma unroll
  for (int r = 0; r < 16; r++) {
    const int q = wq + (r & 3) + 8 * (r >> 2) + 4 * hi;
    const float inv = 1.0f / lsum[q];
#pragma unroll
    for (int dt = 0; dt < 2; dt++) {
      const int d = dt * 32 + l31;
      Qio[base + (size_t)(q0 + q) * HDIM + d] = (bf16_t)(o_acc[dt][r] * inv);
    }
  }
}

// ---------------------------------------------------------------------------
extern "C" void kernel_launch(void* const* d_in, const int* in_sizes, int n_in,
                              void* d_out, int out_size, void* d_ws, size_t ws_size,
                              hipStream_t stream) {
  const float* x = (const float*)d_in[0];      // [B,S,D] f32
  const float* w_qkv = (const float*)d_in[1];  // [D, 3D] f32
  const float* w_out = (const float*)d_in[2];  // [D, D] f32
  const float* b_out = (const float*)d_in[3];  // [D] f32
  float* out = (float*)d_out;                  // [B,S,D] f32

  char* ws = (char*)d_ws;
  bf16_t* wqkv_t = (bf16_t*)ws; ws += (size_t)3 * DD * DD * 2;          // [3D][D]
  bf16_t* wout_t = (bf16_t*)ws; ws += (size_t)DD * DD * 2;              // [D][D]
  bf16_t* q_ws = (bf16_t*)ws;   ws += (size_t)BB * HH * SS * HDIM * 2;  // [B,H,S,HD]
  bf16_t* k_ws = (bf16_t*)ws;                                           // [B,H,S,HD]
  bf16_t* vt_sc = (bf16_t*)d_out;                       // d_out lower half: Vt
  bf16_t* xb = (bf16_t*)d_out + (size_t)BB * SS * DD;   // d_out upper half: x_bf16

  cvt_x<<<(BB * SS * DD) / (256 * 8), 256, 0, stream>>>(x, xb);
  wt_transpose<<<dim3(3 * DD / 64, DD / 64), 256, 0, stream>>>(w_qkv, wqkv_t, DD, 3 * DD);
  wt_transpose<<<dim3(DD / 64, DD / 64), 256, 0, stream>>>(w_out, wout_t, DD, DD);
  gemm_qkv<<<dim3((3 * DD) / 256, (BB * SS) / 256), 512, 0, stream>>>(
      xb, wqkv_t, q_ws, k_ws, vt_sc);
  attn_kernel<<<dim3(SS / 128, BB * HH), 256, 0, stream>>>(q_ws, k_ws, vt_sc);
  gemm_proj<<<dim3(DD / 128, (BB * SS) / 128), 256, 0, stream>>>(
      q_ws, wout_t, out, b_out);
}

// Round 12
// 228.545 us; speedup vs baseline: 1.1533x; 1.1533x over previous
//
#include <hip/hip_runtime.h>

// B=4, S=2048, D=768, H=12, HD=64. I/O f32; internal bf16 MFMA.
// ws: wqkv_t [2304][768] | wout_t [768][768] | q_ws, k_ws [B,H,S,64] (bf16)
// d_out scratch: lower half Vt (bf16 [B,H,HD,S], TRUE s order), upper half x_bf16.
// attn output overwrites q_ws rows in place (block-local; race-free).
// Q is pre-scaled by SCALE*log2(e) at the QKV epilogue (softmax uses raw exp2).
//
// Round-12 = best-measured components reassembled:
//   gemm_bt  : r6 config (128^2, BK=64, dbuf, 1 barrier/step, prefetch-after-
//              barrier) — best measured QKV GEMM (68.4 us; BK32/4buf/256^2
//              all regressed: 74.4 / 76.5 / 105.9).
//   attn     : r7/r8 config (32x32 MFMA, in-register P, two-state pipeline,
//              strided-phase conflict-fixed swizzle) — best measured attn.
//   gemm_proj: folded back into gemm_bt<1> (r6-exact).
#define BB 4
#define SS 2048
#define DD 768
#define HH 12
#define HDIM 64

using bf16_t = __bf16;
typedef __bf16 bf16x8 __attribute__((ext_vector_type(8)));
typedef __bf16 bf16x4 __attribute__((ext_vector_type(4)));
typedef __bf16 bf16x2 __attribute__((ext_vector_type(2)));
typedef float f32x4 __attribute__((ext_vector_type(4)));
typedef float f32x16 __attribute__((ext_vector_type(16)));
typedef unsigned int u32;
typedef unsigned int u32x4 __attribute__((ext_vector_type(4)));

// async global->LDS 16B per lane; LDS dst is wave-uniform base + lane*16
static __device__ __forceinline__ void cp16(void* lds, const void* g) {
  __builtin_amdgcn_global_load_lds(
      (const __attribute__((address_space(1))) u32*)g,
      (__attribute__((address_space(3))) u32*)lds, 16, 0, 0);
}

// ---------------------------------------------------------------------------
// x f32 [M,K] -> bf16 (contiguous copy+convert)
// ---------------------------------------------------------------------------
__global__ void cvt_x(const float* __restrict__ in, bf16_t* __restrict__ out) {
  const size_t i = ((size_t)blockIdx.x * 256 + threadIdx.x) * 8;
  f32x4 f0 = *(const f32x4*)(in + i);
  f32x4 f1 = *(const f32x4*)(in + i + 4);
  bf16x8 v;
#pragma unroll
  for (int j = 0; j < 4; j++) { v[j] = (bf16_t)f0[j]; v[4 + j] = (bf16_t)f1[j]; }
  *(bf16x8*)(out + i) = v;
}

// ---------------------------------------------------------------------------
// Weight transpose + f32->bf16: in [K][N] f32 -> out [N][K] bf16
// ---------------------------------------------------------------------------
__global__ void wt_transpose(const float* __restrict__ in, bf16_t* __restrict__ out,
                             int K, int N) {
  __shared__ bf16_t tile[64][65];
  const int n0 = blockIdx.x * 64, k0 = blockIdx.y * 64;
  const int t = threadIdx.x;       // 256 threads
  const int r = t >> 2;            // 0..63
  const int c0 = (t & 3) * 16;     // 0,16,32,48
  const float* src = in + (size_t)(k0 + r) * N + n0 + c0;
#pragma unroll
  for (int q = 0; q < 4; q++) {
    f32x4 f = *(const f32x4*)(src + q * 4);
#pragma unroll
    for (int j = 0; j < 4; j++) tile[r][c0 + q * 4 + j] = (bf16_t)f[j];
  }
  __syncthreads();
  bf16x8 o0, o1;
#pragma unroll
  for (int j = 0; j < 8; j++) { o0[j] = tile[c0 + j][r]; o1[j] = tile[c0 + 8 + j][r]; }
  *(bf16x8*)(out + (size_t)(n0 + r) * K + k0 + c0) = o0;
  *(bf16x8*)(out + (size_t)(n0 + r) * K + k0 + c0 + 8) = o1;
}

// ---------------------------------------------------------------------------
// GEMM (r6-exact, best measured): C[M,N] = A[M,K] @ Bt[N,K]^T, all-bf16,
// fp32 MFMA accum. 128x128 tile, BK=64, 4 waves, double-buffered LDS
// (64 KB): one barrier per K-step; prefetch for step kt+1 issued right
// after the barrier so its DMA has the whole step to land. XCD-chunked
// bijective swizzle keeps A m-band + B panel L2-resident.
// MODE 0: A = x_bf16 [M,K]; epi scatters Q (pre-scaled by SCALE*log2e), K ->
//         [B,H,S,HD], V -> Vt [B,H,HD,S] in TRUE s order.
// MODE 1: A = bf16 head-interleaved [B,H,S,HD]; epi adds f32 bias, writes f32.
// ---------------------------------------------------------------------------
template <int MODE>
__global__ __launch_bounds__(256, 2)
void gemm_bt(const bf16_t* __restrict__ A, const bf16_t* __restrict__ Bt,
             int M, int N, int K,
             bf16_t* __restrict__ q_out, bf16_t* __restrict__ k_out,
             bf16_t* __restrict__ vt_out,
             float* __restrict__ Cout, const float* __restrict__ bias) {
  __shared__ bf16_t As[2][128][64];
  __shared__ bf16_t Bs[2][128][64];
  const int t = threadIdx.x;
  const int lane = t & 63, wave = t >> 6;
  const int l15 = lane & 15, quad = lane >> 4;
  const int wm = (wave >> 1) * 64, wn = (wave & 1) * 64;

  const int nx = gridDim.x;
  const int L = blockIdx.y * nx + blockIdx.x;
  const int chunk = (nx * gridDim.y) >> 3;
  const int v = (L & 7) * chunk + (L >> 3);
  const int m0 = (v / nx) * 128, n0 = (v % nx) * 128;

  const int srow = lane >> 3;
  const int schunk = ((lane & 7) ^ srow) * 8;
  const int rsw = l15 & 7;

  f32x4 acc[4][4];
#pragma unroll
  for (int i = 0; i < 4; i++)
#pragma unroll
    for (int j = 0; j < 4; j++) acc[i][j] = (f32x4){0.f, 0.f, 0.f, 0.f};

  auto stage = [&](int k0, int buf) {
#pragma unroll
    for (int p = 0; p < 4; p++) {
      const int row = wave * 32 + p * 8 + srow;
      const bf16_t* asrc;
      if (MODE == 0) {
        asrc = A + (size_t)(m0 + row) * K + k0 + schunk;
      } else {
        const int mm = m0 + row, b = mm >> 11, s = mm & 2047, h = k0 >> 6;
        asrc = A + (((size_t)(b * HH + h)) * SS + s) * HDIM + schunk;
      }
      cp16(&As[buf][wave * 32 + p * 8][0], asrc);
      cp16(&Bs[buf][wave * 32 + p * 8][0],
           Bt + (size_t)(n0 + row) * K + k0 + schunk);
    }
  };

  const int NT = K / 64;
  stage(0, 0);

  for (int kt = 0; kt < NT; kt++) {
    const int buf = kt & 1;
    // drains the prefetch for this tile (issued a full iteration ago) and
    // fences last iteration's ds_reads of buf^1 before we overwrite it.
    __syncthreads();
    if (kt + 1 < NT) stage((kt + 1) * 64, buf ^ 1);
#pragma unroll
    for (int kk = 0; kk < 2; kk++) {
      bf16x8 af[4], bfr[4];
#pragma unroll
      for (int i = 0; i < 4; i++)
        af[i] = *(const bf16x8*)&As[buf][wm + i * 16 + l15][((kk * 4 + quad) ^ rsw) * 8];
#pragma unroll
      for (int j = 0; j < 4; j++)
        bfr[j] = *(const bf16x8*)&Bs[buf][wn + j * 16 + l15][((kk * 4 + quad) ^ rsw) * 8];
#pragma unroll
      for (int i = 0; i < 4; i++)
#pragma unroll
        for (int j = 0; j < 4; j++)
          acc[i][j] = __builtin_amdgcn_mfma_f32_16x16x32_bf16(af[i], bfr[j], acc[i][j], 0, 0, 0);
    }
  }

  // Epilogue. C/D layout: row = quad*4 + reg, col = l15.
  const float QSCALE = 0.125f * 1.44269504088896340736f;  // SCALE * log2(e)
#pragma unroll
  for (int i = 0; i < 4; i++) {
    const int mbase = m0 + wm + i * 16 + quad * 4;
#pragma unroll
    for (int j = 0; j < 4; j++) {
      const int n = n0 + wn + j * 16 + l15;
#pragma unroll
      for (int r = 0; r < 4; r++) {
        const float v = acc[i][j][r];
        const int mm = mbase + r;
        if (MODE == 0) {
          const int sel = n / DD;          // 0:Q 1:K 2:V
          const int rem = n - sel * DD;
          const int h = rem >> 6, d = rem & 63;
          const int b = mm >> 11, s = mm & 2047;
          if (sel == 2) {
            vt_out[((size_t)(b * HH + h) * HDIM + d) * SS + s] = (bf16_t)v;
          } else {
            const size_t idx = (((size_t)(b * HH + h)) * SS + s) * HDIM + d;
            if (sel == 0) q_out[idx] = (bf16_t)(v * QSCALE);
            else k_out[idx] = (bf16_t)v;
          }
        } else {
          Cout[(size_t)mm * N + n] = v + bias[n];
        }
      }
    }
  }
}

// ---------------------------------------------------------------------------
// Flash attention (r7/r8-exact, best measured): streaming softmax, 32x32
// MFMA, in-register P (T12), two-state pipeline (QK(cur+1) issued before
// softmax(cur) so SM VALU overlaps QK matrix time).
// Conflict fix: stage chunk = (lane&7)^srow^((wave*2+p)&3), read key
// rsw = (l31&7)^(l31>>3) (strided lane%8 phase model from r5/r6 counters).
// Fragment algebra (verified r5): S^T = mfma(K,Q): lane(q=l31,hi) owns
// P[q][k=8g+4hi+m]; cvt_pk pairs w[g][i]; permlane32_swap A=w[2sub],
// B=w[2sub+1], frag {A0,A1,B0,B1} = PV A-operand. P in TRUE s order.
// K staged 2 tiles ahead, V 1 ahead; all overwrites fenced by the barrier
// preceding them. XCD swizzle: 96 blocks/XCD = 6 whole heads (L2-resident).
// ---------------------------------------------------------------------------
__global__ __launch_bounds__(256, 3)
void attn_kernel(bf16_t* __restrict__ Qio, const bf16_t* __restrict__ Kg,
                 const bf16_t* __restrict__ Vt) {
  __shared__ bf16_t Ks[2][64][64];   // [buf][s_k][d]
  __shared__ bf16_t Vts[2][64][64];  // [buf][d][s]  (true s order)
  __shared__ float lsum[128];
  const int t = threadIdx.x;
  const int lane = t & 63, wave = t >> 6;
  const int l31 = lane & 31, hi = lane >> 5;

  // bijective XCD-aware remap: linear id -> contiguous chunk per XCD
  const int L = blockIdx.y * gridDim.x + blockIdx.x;        // 0..767
  const int v = (L & 7) * ((16 * BB * HH) / 8) + (L >> 3);  // 96 blocks/XCD
  const int bh = v >> 4;
  const int q0 = (v & 15) * 128;

  const size_t base = (size_t)bh * SS * HDIM;   // Q,K: [bh][s][d]
  const size_t baset = (size_t)bh * HDIM * SS;  // Vt:  [bh][d][s]
  const int wq = wave * 32;
  const int srow = lane >> 3;                   // 0..7
  const int rsw = (l31 & 7) ^ (l31 >> 3);       // read-side swizzle key

  // Q fragments (one-time, B-operand): qf[kd] = Q[q0+wq+l31][kd*16+hi*8 ..+7]
  bf16x8 qf[4];
#pragma unroll
  for (int kd = 0; kd < 4; kd++)
    qf[kd] = *(const bf16x8*)(Qio + base + (size_t)(q0 + wq + l31) * HDIM +
                              kd * 16 + hi * 8);

  float l_lane = 0.f;
  f32x16 o_acc[2];
#pragma unroll
  for (int dt = 0; dt < 2; dt++)
#pragma unroll
    for (int r = 0; r < 16; r++) o_acc[dt][r] = 0.f;

  f32x16 sA[2], sB[2];

  auto stageK = [&](int k0, int buf) {
#pragma unroll
    for (int p = 0; p < 2; p++) {
      const int sc = ((lane & 7) ^ srow ^ ((wave * 2 + p) & 3)) * 8;
      cp16(&Ks[buf][wave * 16 + p * 8][0],
           Kg + base + (size_t)(k0 + wave * 16 + p * 8 + srow) * HDIM + sc);
    }
  };
  auto stageV = [&](int k0, int buf) {
#pragma unroll
    for (int p = 0; p < 2; p++) {
      const int sc = ((lane & 7) ^ srow ^ ((wave * 2 + p) & 3)) * 8;
      cp16(&Vts[buf][wave * 16 + p * 8][0],
           Vt + baset + (size_t)(wave * 16 + p * 8 + srow) * SS + k0 + sc);
    }
  };

  // S^T = K @ Q^T for one 64-k tile into s[2] (swapped operands)
  auto qk = [&](int buf, f32x16 (&s)[2]) {
    __builtin_amdgcn_s_setprio(1);
#pragma unroll
    for (int ct = 0; ct < 2; ct++) {
#pragma unroll
      for (int r = 0; r < 16; r++) s[ct][r] = 0.f;
#pragma unroll
      for (int kd = 0; kd < 4; kd++) {
        bf16x8 kf = *(const bf16x8*)&Ks[buf][ct * 32 + l31][((2 * kd + hi) ^ rsw) * 8];
        s[ct] = __builtin_amdgcn_mfma_f32_32x32x16_bf16(kf, qf[kd], s[ct], 0, 0, 0);
      }
    }
    __builtin_amdgcn_s_setprio(0);
  };

  // softmax(s) in-register -> pa frags; O += P @ V[buf]
  auto smpv = [&](int buf, const f32x16 (&sT)[2]) {
    bf16x8 pa[4];
#pragma unroll
    for (int ct = 0; ct < 2; ct++) {
      float p[16];
#pragma unroll
      for (int r = 0; r < 16; r++) p[r] = __builtin_amdgcn_exp2f(sT[ct][r]);
#pragma unroll
      for (int r = 0; r < 16; r += 4)
        l_lane += (p[r] + p[r + 1]) + (p[r + 2] + p[r + 3]);
      u32 w[4][2];
#pragma unroll
      for (int g = 0; g < 4; g++)
#pragma unroll
        for (int i = 0; i < 2; i++) {
          bf16x2 pk = {(bf16_t)p[4 * g + 2 * i], (bf16_t)p[4 * g + 2 * i + 1]};
          w[g][i] = *(u32*)&pk;
        }
#pragma unroll
      for (int sub = 0; sub < 2; sub++) {
        u32 a0 = w[2 * sub][0], b0 = w[2 * sub + 1][0];
        u32 a1 = w[2 * sub][1], b1 = w[2 * sub + 1][1];
        asm volatile("v_permlane32_swap_b32 %0, %1" : "+v"(a0), "+v"(b0));
        asm volatile("v_permlane32_swap_b32 %0, %1" : "+v"(a1), "+v"(b1));
        u32x4 fr = {a0, a1, b0, b1};
        pa[ct * 2 + sub] = *(bf16x8*)&fr;
      }
    }
    __builtin_amdgcn_s_setprio(1);
#pragma unroll
    for (int kk = 0; kk < 4; kk++)
#pragma unroll
      for (int dt = 0; dt < 2; dt++) {
        bf16x8 vf = *(const bf16x8*)&Vts[buf][dt * 32 + l31][((2 * kk + hi) ^ rsw) * 8];
        o_acc[dt] = __builtin_amdgcn_mfma_f32_32x32x16_bf16(pa[kk], vf, o_acc[dt], 0, 0, 0);
      }
    __builtin_amdgcn_s_setprio(0);
  };

  // Prologue: K[0],K[1],V[0] staged; QK(0)->sA; extra barrier so the loop's
  // first stageK(2)->Ks[0] can't race another wave still reading Ks[0].
  stageK(0, 0); stageK(64, 1); stageV(0, 0);
  __syncthreads();
  qk(0, sA);
  __syncthreads();

#pragma unroll 1
  for (int it = 0; it < 30; it += 2) {
    // even: cur=it (sA), next=it+1 (sB)
    stageK((it + 2) * 64, 0);
    stageV((it + 1) * 64, 1);
    qk(1, sB);        // QK(it+1) issued EARLY; SM(it) VALU overlaps it
    smpv(0, sA);      // softmax+PV for cur=it, V in Vts[0]
    __syncthreads();
    // odd: cur=it+1 (sB), next=it+2 (sA)
    stageK((it + 3) * 64, 1);
    stageV((it + 2) * 64, 0);
    qk(0, sA);        // QK(it+2)
    smpv(1, sB);      // PV(it+1), V in Vts[1]
    __syncthreads();
  }
  // tail pair it=30,31: no more K to stage; V[31] into Vts[1]
  stageV(31 * 64, 1);
  qk(1, sB);          // QK(31)
  smpv(0, sA);        // PV(30)
  __syncthreads();
  smpv(1, sB);        // PV(31)

  // l: lane-local sum covers k-parity == hi; partner (^32) has the rest.
  const float lf = l_lane + __shfl_xor(l_lane, 32);
  lsum[wq + l31] = lf;  // both halves write the same value; own-wave region
  // O write: col = d = dt*32+l31, row = q = (r&3)+8*(r>>2)+4*hi (+wq).
#pragma unroll
  for (int r = 0; r < 16; r++) {
    const int q = wq + (r & 3) + 8 * (r >> 2) + 4 * hi;
    const float inv = 1.0f / lsum[q];
#pragma unroll
    for (int dt = 0; dt < 2; dt++) {
      const int d = dt * 32 + l31;
      Qio[base + (size_t)(q0 + q) * HDIM + d] = (bf16_t)(o_acc[dt][r] * inv);
    }
  }
}

// ---------------------------------------------------------------------------
extern "C" void kernel_launch(void* const* d_in, const int* in_sizes, int n_in,
                              void* d_out, int out_size, void* d_ws, size_t ws_size,
                              hipStream_t stream) {
  const float* x = (const float*)d_in[0];      // [B,S,D] f32
  const float* w_qkv = (const float*)d_in[1];  // [D, 3D] f32
  const float* w_out = (const float*)d_in[2];  // [D, D] f32
  const float* b_out = (const float*)d_in[3];  // [D] f32
  float* out = (float*)d_out;                  // [B,S,D] f32

  char* ws = (char*)d_ws;
  bf16_t* wqkv_t = (bf16_t*)ws; ws += (size_t)3 * DD * DD * 2;          // [3D][D]
  bf16_t* wout_t = (bf16_t*)ws; ws += (size_t)DD * DD * 2;              // [D][D]
  bf16_t* q_ws = (bf16_t*)ws;   ws += (size_t)BB * HH * SS * HDIM * 2;  // [B,H,S,HD]
  bf16_t* k_ws = (bf16_t*)ws;                                           // [B,H,S,HD]
  bf16_t* vt_sc = (bf16_t*)d_out;                       // d_out lower half: Vt
  bf16_t* xb = (bf16_t*)d_out + (size_t)BB * SS * DD;   // d_out upper half: x_bf16

  cvt_x<<<(BB * SS * DD) / (256 * 8), 256, 0, stream>>>(x, xb);
  wt_transpose<<<dim3(3 * DD / 64, DD / 64), 256, 0, stream>>>(w_qkv, wqkv_t, DD, 3 * DD);
  wt_transpose<<<dim3(DD / 64, DD / 64), 256, 0, stream>>>(w_out, wout_t, DD, DD);
  gemm_bt<0><<<dim3(3 * DD / 128, BB * SS / 128), 256, 0, stream>>>(
      xb, wqkv_t, BB * SS, 3 * DD, DD, q_ws, k_ws, vt_sc, nullptr, nullptr);
  attn_kernel<<<dim3(SS / 128, BB * HH), 256, 0, stream>>>(q_ws, k_ws, vt_sc);
  gemm_bt<1><<<dim3(DD / 128, BB * SS / 128), 256, 0, stream>>>(
      q_ws, wout_t, BB * SS, DD, DD, nullptr, nullptr, nullptr, out, b_out);
}